// Round 3
// baseline (101.536 us; speedup 1.0000x reference)
//
#include <hip/hip_runtime.h>
#include <hip/hip_bf16.h>

#define T_DIM 2048
#define B_DIM 2
#define E_DIM 256
#define H_DIM 8
#define D_DIM 32
#define M_DIM (T_DIM*B_DIM)   // 4096
#define SPLIT 4
#define S_CHUNK (T_DIM/SPLIT) // 512

typedef __bf16 bf16x8 __attribute__((ext_vector_type(8)));
typedef __bf16 bf16x4 __attribute__((ext_vector_type(4)));
typedef float  f32x4  __attribute__((ext_vector_type(4)));

// ---------------- Kernel 0: fused f32 -> bf16 convert ----------------
__global__ __launch_bounds__(256)
void cvt_all_kernel(const float* __restrict__ query,
                    const float* __restrict__ Wq, const float* __restrict__ Wk,
                    const float* __restrict__ Wv, const float* __restrict__ Wo,
                    __bf16* __restrict__ Xbf, __bf16* __restrict__ Wdst) {
    int idx = (blockIdx.x * 256 + threadIdx.x) * 4;   // elem index, 4 per thread
    const int NX = M_DIM * E_DIM;                     // 1048576
    float4 v;
    __bf16* dst;
    if (idx < NX) {
        v = *(const float4*)(query + idx);
        dst = Xbf + idx;
    } else {
        int j = idx - NX;                             // 0 .. 262143
        int which = j >> 16;                          // 0..3
        int off = j & 65535;
        const float* src = (which == 0) ? Wq : (which == 1) ? Wk : (which == 2) ? Wv : Wo;
        v = *(const float4*)(src + off);
        dst = Wdst + j;
    }
    bf16x4 o;
    o[0] = (__bf16)v.x; o[1] = (__bf16)v.y; o[2] = (__bf16)v.z; o[3] = (__bf16)v.w;
    *(bf16x4*)dst = o;
}

// ---------------- Kernel 1: fused QKV projection ----------------
__global__ __launch_bounds__(256)
void qkv_kernel(const __bf16* __restrict__ X, const __bf16* __restrict__ Wall,
                const float* __restrict__ bq, const float* __restrict__ bk, const float* __restrict__ bv,
                __bf16* __restrict__ qh, __bf16* __restrict__ kh, __bf16* __restrict__ vT) {
    __shared__ __align__(16) __bf16 Xs[64][136];
    __shared__ __align__(16) __bf16 Ws[64][136];
    const int m0 = blockIdx.x * 64;
    const int which = blockIdx.y >> 2;        // 0 q, 1 k, 2 v
    const int n0 = (blockIdx.y & 3) * 64;
    const __bf16* W = Wall + (size_t)which * E_DIM * E_DIM;
    const float* bias = (which == 0) ? bq : (which == 1) ? bk : bv;
    const int tid = threadIdx.x;
    const int wid = tid >> 6, lane = tid & 63;
    const int wm = (wid & 1) * 32, wn = (wid >> 1) * 32;
    const int lr = lane & 15, lg = lane >> 4;

    f32x4 acc[2][2] = {};
    for (int kc = 0; kc < 2; ++kc) {
        for (int c = tid; c < 1024; c += 256) {
            int row = c >> 4, col = (c & 15) * 8;
            *(bf16x8*)&Xs[row][col] = *(const bf16x8*)&X[(size_t)(m0 + row) * E_DIM + kc * 128 + col];
            *(bf16x8*)&Ws[row][col] = *(const bf16x8*)&W[(size_t)(n0 + row) * E_DIM + kc * 128 + col];
        }
        __syncthreads();
#pragma unroll
        for (int ks = 0; ks < 4; ++ks) {
            bf16x8 a0 = *(const bf16x8*)&Xs[wm + lr][ks * 32 + lg * 8];
            bf16x8 a1 = *(const bf16x8*)&Xs[wm + 16 + lr][ks * 32 + lg * 8];
            bf16x8 b0 = *(const bf16x8*)&Ws[wn + lr][ks * 32 + lg * 8];
            bf16x8 b1 = *(const bf16x8*)&Ws[wn + 16 + lr][ks * 32 + lg * 8];
            acc[0][0] = __builtin_amdgcn_mfma_f32_16x16x32_bf16(a0, b0, acc[0][0], 0, 0, 0);
            acc[0][1] = __builtin_amdgcn_mfma_f32_16x16x32_bf16(a0, b1, acc[0][1], 0, 0, 0);
            acc[1][0] = __builtin_amdgcn_mfma_f32_16x16x32_bf16(a1, b0, acc[1][0], 0, 0, 0);
            acc[1][1] = __builtin_amdgcn_mfma_f32_16x16x32_bf16(a1, b1, acc[1][1], 0, 0, 0);
        }
        __syncthreads();
    }
    const float scale = 0.17677669529663687f;  // 1/sqrt(32)
#pragma unroll
    for (int mt = 0; mt < 2; ++mt) {
#pragma unroll
        for (int nt = 0; nt < 2; ++nt) {
            int n = n0 + wn + nt * 16 + lr;            // 0..255
            float bb = bias[n];
            int h = n >> 5, d = n & 31;
#pragma unroll
            for (int r = 0; r < 4; ++r) {
                int m = m0 + wm + mt * 16 + lg * 4 + r;
                int t = m >> 1, b = m & 1;
                float v = acc[mt][nt][r] + bb;
                if (which == 0) {
                    v *= scale;
                    qh[((size_t)(b * H_DIM + h) * T_DIM + t) * D_DIM + d] = (__bf16)v;
                } else if (which == 1) {
                    kh[((size_t)(b * H_DIM + h) * T_DIM + t) * D_DIM + d] = (__bf16)v;
                } else {
                    vT[((size_t)(b * H_DIM + h) * D_DIM + d) * T_DIM + t] = (__bf16)v;
                }
            }
        }
    }
}

// ---------------- Kernel 2: flash attention, barrier-free ----------------
// grid (T/64, B*H, SPLIT), block 256 (4 waves), each wave fully independent.
// Swapped QK^T: S^T tile [s][t] via mfma(K, Q, bias^T). Lane owns column t = lane&15.
__global__ __launch_bounds__(256, 4)
void attn_kernel(const __bf16* __restrict__ qh, const __bf16* __restrict__ kh,
                 const __bf16* __restrict__ vT, const float* __restrict__ attn_bias,
                 float* __restrict__ po, float* __restrict__ pml) {
    __shared__ __align__(16) __bf16 Ps[4][16][72]; // per-wave P tile [t][s], pad 72
    const int t0 = blockIdx.x * 64;
    const int bh = blockIdx.y;
    const int sp = blockIdx.z;
    const int sbase = sp * S_CHUNK;
    const int b = bh >> 3;
    const int tid = threadIdx.x, wid = tid >> 6, lane = tid & 63;
    const int lr = lane & 15, lg = lane >> 4;
    const int lg4 = lg * 4;
    const int tmy = t0 + wid * 16 + lr;         // this lane's q-row (lr domain)
    const float LOG2E = 1.4426950408889634f;

    // Q fragment, used as B-operand (n = t): lane n=lr holds d-chunk lg*8
    bf16x8 qf = *(const bf16x8*)&qh[((size_t)bh * T_DIM + tmy) * D_DIM + lg * 8];

    const float*  brow  = attn_bias + ((size_t)b * T_DIM + tmy) * T_DIM;
    const __bf16* kbase = kh + (size_t)bh * T_DIM * D_DIM;
    const __bf16* vbase = vT + (size_t)bh * D_DIM * T_DIM;

    float m = -1e30f, l = 0.f;
    f32x4 o[2] = {};

    for (int st = 0; st < S_CHUNK / 64; ++st) {
        const int s0 = sbase + st * 64;

        // --- all global loads up front (no barriers anywhere) ---
        f32x4 cb[4];
        bf16x8 kf[4];
#pragma unroll
        for (int nt = 0; nt < 4; ++nt) {
            cb[nt] = *(const f32x4*)&brow[s0 + nt * 16 + lg4];                     // bias^T C-operand
            kf[nt] = *(const bf16x8*)&kbase[(size_t)(s0 + nt * 16 + lr) * D_DIM + lg * 8]; // K A-frag
        }
        bf16x8 vf[2][2];
#pragma unroll
        for (int kt = 0; kt < 2; ++kt)
#pragma unroll
            for (int dt = 0; dt < 2; ++dt)
                vf[kt][dt] = *(const bf16x8*)&vbase[(size_t)(dt * 16 + lr) * T_DIM + s0 + kt * 32 + lg * 8];

        // --- S^T = K Q^T + bias^T : D[s][t], col = t = lr, row = s = lg*4+r ---
        f32x4 s[4];
#pragma unroll
        for (int nt = 0; nt < 4; ++nt)
            s[nt] = __builtin_amdgcn_mfma_f32_16x16x32_bf16(kf[nt], qf, cb[nt], 0, 0, 0);

        // --- in-lane softmax: lane holds 16 scores of row tmy ---
        float mx = fmaxf(fmaxf(s[0][0], s[0][1]), fmaxf(s[0][2], s[0][3]));
#pragma unroll
        for (int nt = 1; nt < 4; ++nt)
            mx = fmaxf(mx, fmaxf(fmaxf(s[nt][0], s[nt][1]), fmaxf(s[nt][2], s[nt][3])));
        mx = fmaxf(mx, __shfl_xor(mx, 16));
        mx = fmaxf(mx, __shfl_xor(mx, 32));
        float mnew = fmaxf(m, mx);
        float sc = exp2f((m - mnew) * LOG2E);
        float nm2 = -mnew * LOG2E;
        m = mnew;
        float p[4][4];
        float sum = 0.f;
#pragma unroll
        for (int nt = 0; nt < 4; ++nt)
#pragma unroll
            for (int r = 0; r < 4; ++r) {
                float pv = exp2f(fmaf(s[nt][r], LOG2E, nm2));
                p[nt][r] = pv;
                sum += pv;
            }
        sum += __shfl_xor(sum, 16);
        sum += __shfl_xor(sum, 32);
        l = l * sc + sum;

        // rescale o (o rows live in t = lg*4+r domain -> broadcast sc)
#pragma unroll
        for (int r = 0; r < 4; ++r) {
            float scr = __shfl(sc, lg4 + r);
            o[0][r] *= scr;
            o[1][r] *= scr;
        }

        // --- P -> per-wave LDS (vectorized), then PV ---
#pragma unroll
        for (int nt = 0; nt < 4; ++nt) {
            bf16x4 pk;
#pragma unroll
            for (int r = 0; r < 4; ++r) pk[r] = (__bf16)p[nt][r];
            *(bf16x4*)&Ps[wid][lr][nt * 16 + lg4] = pk;
        }
#pragma unroll
        for (int kt = 0; kt < 2; ++kt) {
            bf16x8 pf = *(const bf16x8*)&Ps[wid][lr][kt * 32 + lg * 8];
#pragma unroll
            for (int dt = 0; dt < 2; ++dt)
                o[dt] = __builtin_amdgcn_mfma_f32_16x16x32_bf16(pf, vf[kt][dt], o[dt], 0, 0, 0);
        }
    }

    // epilogue: unnormalized partials. o row r = t0+wid*16+lg*4+r, col = dt*16+lr
#pragma unroll
    for (int r = 0; r < 4; ++r) {
        int t = t0 + wid * 16 + lg4 + r;
        size_t rw = ((size_t)bh * T_DIM + t) * SPLIT + sp;
        po[rw * D_DIM + lr] = o[0][r];
        po[rw * D_DIM + 16 + lr] = o[1][r];
    }
    if (lg == 0) {
        size_t rw = ((size_t)bh * T_DIM + tmy) * SPLIT + sp;
        pml[rw * 2 + 0] = m;
        pml[rw * 2 + 1] = l;
    }
}

// ---------------- Kernel 2b: combine split-S partials ----------------
__global__ __launch_bounds__(256)
void combine_kernel(const float* __restrict__ po, const float* __restrict__ pml,
                    __bf16* __restrict__ attn) {
    int idx = blockIdx.x * 256 + threadIdx.x;
    int row = idx >> 3, dg = idx & 7;
    int bh = row >> 11, t = row & 2047;
    int b = bh >> 3, h = bh & 7;

    float mv[SPLIT], lv[SPLIT];
    float M = -1e30f;
#pragma unroll
    for (int sp2 = 0; sp2 < SPLIT; ++sp2) {
        mv[sp2] = pml[((size_t)row * SPLIT + sp2) * 2 + 0];
        lv[sp2] = pml[((size_t)row * SPLIT + sp2) * 2 + 1];
        M = fmaxf(M, mv[sp2]);
    }
    float L = 0.f;
    f32x4 acc = {};
#pragma unroll
    for (int sp2 = 0; sp2 < SPLIT; ++sp2) {
        float w = __expf(mv[sp2] - M);
        L += lv[sp2] * w;
        f32x4 v = *(const f32x4*)&po[((size_t)row * SPLIT + sp2) * D_DIM + dg * 4];
#pragma unroll
        for (int j = 0; j < 4; ++j) acc[j] += w * v[j];
    }
    float inv = 1.0f / L;
    bf16x4 o4;
#pragma unroll
    for (int j = 0; j < 4; ++j) o4[j] = (__bf16)(acc[j] * inv);
    *(bf16x4*)&attn[((size_t)(t * B_DIM + b)) * E_DIM + h * D_DIM + dg * 4] = o4;
}

// ---------------- Kernel 3: output projection ----------------
__global__ __launch_bounds__(256)
void oproj_kernel(const __bf16* __restrict__ X, const __bf16* __restrict__ Wo,
                  const float* __restrict__ bo, float* __restrict__ out) {
    __shared__ __align__(16) __bf16 Xs[64][136];
    __shared__ __align__(16) __bf16 Ws[64][136];
    const int m0 = blockIdx.x * 64;
    const int n0 = blockIdx.y * 64;
    const int tid = threadIdx.x;
    const int wid = tid >> 6, lane = tid & 63;
    const int wm = (wid & 1) * 32, wn = (wid >> 1) * 32;
    const int lr = lane & 15, lg = lane >> 4;

    f32x4 acc[2][2] = {};
    for (int kc = 0; kc < 2; ++kc) {
        for (int c = tid; c < 1024; c += 256) {
            int row = c >> 4, col = (c & 15) * 8;
            *(bf16x8*)&Xs[row][col] = *(const bf16x8*)&X[(size_t)(m0 + row) * E_DIM + kc * 128 + col];
            *(bf16x8*)&Ws[row][col] = *(const bf16x8*)&Wo[(size_t)(n0 + row) * E_DIM + kc * 128 + col];
        }
        __syncthreads();
#pragma unroll
        for (int ks = 0; ks < 4; ++ks) {
            bf16x8 a0 = *(const bf16x8*)&Xs[wm + lr][ks * 32 + lg * 8];
            bf16x8 a1 = *(const bf16x8*)&Xs[wm + 16 + lr][ks * 32 + lg * 8];
            bf16x8 b0 = *(const bf16x8*)&Ws[wn + lr][ks * 32 + lg * 8];
            bf16x8 b1 = *(const bf16x8*)&Ws[wn + 16 + lr][ks * 32 + lg * 8];
            acc[0][0] = __builtin_amdgcn_mfma_f32_16x16x32_bf16(a0, b0, acc[0][0], 0, 0, 0);
            acc[0][1] = __builtin_amdgcn_mfma_f32_16x16x32_bf16(a0, b1, acc[0][1], 0, 0, 0);
            acc[1][0] = __builtin_amdgcn_mfma_f32_16x16x32_bf16(a1, b0, acc[1][0], 0, 0, 0);
            acc[1][1] = __builtin_amdgcn_mfma_f32_16x16x32_bf16(a1, b1, acc[1][1], 0, 0, 0);
        }
        __syncthreads();
    }
#pragma unroll
    for (int mt = 0; mt < 2; ++mt) {
#pragma unroll
        for (int nt = 0; nt < 2; ++nt) {
            int n = n0 + wn + nt * 16 + lr;
            float bb = bo[n];
#pragma unroll
            for (int r = 0; r < 4; ++r) {
                int m = m0 + wm + mt * 16 + lg * 4 + r;
                out[(size_t)m * E_DIM + n] = acc[mt][nt][r] + bb;
            }
        }
    }
}

extern "C" void kernel_launch(void* const* d_in, const int* in_sizes, int n_in,
                              void* d_out, int out_size, void* d_ws, size_t ws_size,
                              hipStream_t stream) {
    const float* query     = (const float*)d_in[0];
    const float* attn_bias = (const float*)d_in[1];
    const float* Wq = (const float*)d_in[2];
    const float* bq = (const float*)d_in[3];
    const float* Wk = (const float*)d_in[4];
    const float* bk = (const float*)d_in[5];
    const float* Wv = (const float*)d_in[6];
    const float* bv = (const float*)d_in[7];
    const float* Wo = (const float*)d_in[8];
    const float* bo = (const float*)d_in[9];
    float* out = (float*)d_out;

    char* ws = (char*)d_ws;
    __bf16* Xbf  = (__bf16*)(ws);                         // 2 MB
    __bf16* Wall = (__bf16*)(ws + 2097152);               // 4 x 128 KB contiguous (q,k,v,o)
    __bf16* qhp  = (__bf16*)(ws + 2621440);               // [B][H][T][D] 2 MB
    __bf16* khp  = (__bf16*)(ws + 4718592);               // [B][H][T][D] 2 MB
    __bf16* vTp  = (__bf16*)(ws + 6815744);               // [B][H][D][T] 2 MB
    __bf16* attn = (__bf16*)(ws + 8912896);               // [M][E] 2 MB
    float*  po   = (float*)(ws + 11010048);               // [BH*T][SPLIT][32] f32 = 16 MB
    float*  pml  = (float*)(ws + 27787264);               // [BH*T][SPLIT][2]  f32 = 1 MB

    cvt_all_kernel<<<dim3((M_DIM * E_DIM + 4 * E_DIM * E_DIM) / 1024), 256, 0, stream>>>(
        query, Wq, Wk, Wv, Wo, Xbf, Wall);

    qkv_kernel<<<dim3(M_DIM / 64, 12), 256, 0, stream>>>(Xbf, Wall, bq, bk, bv, qhp, khp, vTp);

    attn_kernel<<<dim3(T_DIM / 64, B_DIM * H_DIM, SPLIT), 256, 0, stream>>>(
        qhp, khp, vTp, attn_bias, po, pml);
    combine_kernel<<<dim3(B_DIM * H_DIM * T_DIM * 8 / 256), 256, 0, stream>>>(po, pml, attn);

    oproj_kernel<<<dim3(M_DIM / 64, E_DIM / 64), 256, 0, stream>>>(
        attn, Wall + 3 * E_DIM * E_DIM, bo, out);
}